// Round 19
// baseline (221.344 us; speedup 1.0000x reference)
//
#include <hip/hip_runtime.h>
#include <hip/hip_fp16.h>

#define NN 100000
#define EE 1600000
#define NPB 256                      // partition blocks
#define EPB (EE / NPB)               // 6250 edges per partition block
#define NGRP2 200                    // dst ranges (counting-sort blocks)
#define GR2 (NN / NGRP2)             // 500 nodes per range
#define CCAP 10240                   // LDS sort capacity (mean 8000, +25 sigma)
#define PSB 50                       // pscan blocks (51200 / 1024)

typedef _Float16 f16x8 __attribute__((ext_vector_type(8)));
typedef float f32x4 __attribute__((ext_vector_type(4)));

// ---------- MFMA GEMM (Nx128)@(128x128), fp16 in/out, fused el/er ----------
// 128 rows/block (2 row-tiles per wave) amortizes the 32KB Wt staging.
// SWAPPED operands: lane holds h[row0+...+lr][ct*16+lg*4+{0..3}].
template <int INHALF>
__global__ __launch_bounds__(256) void gemm_el_k(const void* __restrict__ Xv,
                                                 const __half* __restrict__ Wt,
                                                 const float* __restrict__ al,
                                                 const float* __restrict__ ar,
                                                 __half* __restrict__ Hout,
                                                 float* __restrict__ el,
                                                 float* __restrict__ er) {
    __shared__ alignas(16) unsigned short Xs[128 * 128];  // 32KB
    __shared__ alignas(16) unsigned short Ws[128 * 128];  // 32KB
    int t = threadIdx.x;
    int row0 = blockIdx.x * 128;

    // stage Wt -> Ws (2048 x 16B chunks)
    {
        const uint4* g = (const uint4*)Wt;
#pragma unroll
        for (int j = 0; j < 8; ++j) {
            int c = j * 256 + t;
            uint4 v = g[c];
            int n = c >> 4, kb = (c & 15) << 4;
            *(uint4*)((char*)Ws + n * 256 + (kb ^ ((n & 7) << 4))) = v;
        }
    }
    // stage X -> Xs (2048 x 16B fp16 chunks), fp32->fp16 convert if !INHALF
#pragma unroll
    for (int j = 0; j < 8; ++j) {
        int c = j * 256 + t;
        int row = c >> 4, kb = (c & 15) << 4;
        int grow = row0 + row; if (grow >= NN) grow = NN - 1;
        uint4 pk;
        if (INHALF) {
            pk = ((const uint4*)Xv)[(size_t)grow * 16 + (c & 15)];
        } else {
            const float4* xp = (const float4*)Xv + (size_t)grow * 32 + (c & 15) * 2;
            float4 v0 = xp[0], v1 = xp[1];
            __half2 h01 = __floats2half2_rn(v0.x, v0.y);
            __half2 h23 = __floats2half2_rn(v0.z, v0.w);
            __half2 h45 = __floats2half2_rn(v1.x, v1.y);
            __half2 h67 = __floats2half2_rn(v1.z, v1.w);
            pk = make_uint4(__builtin_bit_cast(unsigned, h01),
                            __builtin_bit_cast(unsigned, h23),
                            __builtin_bit_cast(unsigned, h45),
                            __builtin_bit_cast(unsigned, h67));
        }
        *(uint4*)((char*)Xs + row * 256 + (kb ^ ((row & 7) << 4))) = pk;
    }
    __syncthreads();

    int w = t >> 6, lane = t & 63;
    int lr = lane & 15, lg = lane >> 4;

    f32x4 acc[2][8] = {};
#pragma unroll
    for (int ks = 0; ks < 4; ++ks) {
        int kb = ks * 64 + lg * 16;  // BYTES: k-slice (lane>>4)*8 halves
        int xr0 = w * 32 + lr, xr1 = w * 32 + 16 + lr;
        f16x8 b0 = *(const f16x8*)((char*)Xs + xr0 * 256 + (kb ^ ((xr0 & 7) << 4)));
        f16x8 b1 = *(const f16x8*)((char*)Xs + xr1 * 256 + (kb ^ ((xr1 & 7) << 4)));
#pragma unroll
        for (int ct = 0; ct < 8; ++ct) {
            int wrow = ct * 16 + lr;
            f16x8 a = *(const f16x8*)((char*)Ws + wrow * 256 + (kb ^ ((wrow & 7) << 4)));
            acc[0][ct] = __builtin_amdgcn_mfma_f32_16x16x32_f16(a, b0, acc[0][ct], 0, 0, 0);
            acc[1][ct] = __builtin_amdgcn_mfma_f32_16x16x32_f16(a, b1, acc[1][ct], 0, 0, 0);
        }
    }

#pragma unroll
    for (int rt = 0; rt < 2; ++rt) {
        int grow = row0 + w * 32 + rt * 16 + lr;
        bool valid = grow < NN;
        if (valid) {
            __half* hp = Hout + (size_t)grow * 128 + lg * 4;
#pragma unroll
            for (int ct = 0; ct < 8; ++ct) {
                __half2 p0 = __floats2half2_rn(acc[rt][ct][0], acc[rt][ct][1]);
                __half2 p1 = __floats2half2_rn(acc[rt][ct][2], acc[rt][ct][3]);
                uint2 pk = make_uint2(__builtin_bit_cast(unsigned, p0),
                                      __builtin_bit_cast(unsigned, p1));
                *(uint2*)(hp + ct * 16) = pk;
            }
        }
        float pl[4] = {}, pr[4] = {};
#pragma unroll
        for (int ct = 0; ct < 8; ++ct) {
            int hd = ct >> 1;
            float4 a_l = *(const float4*)&al[ct * 16 + lg * 4];
            float4 a_r = *(const float4*)&ar[ct * 16 + lg * 4];
            pl[hd] += acc[rt][ct][0] * a_l.x + acc[rt][ct][1] * a_l.y +
                      acc[rt][ct][2] * a_l.z + acc[rt][ct][3] * a_l.w;
            pr[hd] += acc[rt][ct][0] * a_r.x + acc[rt][ct][1] * a_r.y +
                      acc[rt][ct][2] * a_r.z + acc[rt][ct][3] * a_r.w;
        }
#pragma unroll
        for (int hd = 0; hd < 4; ++hd) {
            pl[hd] += __shfl_xor(pl[hd], 16, 64);
            pl[hd] += __shfl_xor(pl[hd], 32, 64);
            pr[hd] += __shfl_xor(pr[hd], 16, 64);
            pr[hd] += __shfl_xor(pr[hd], 32, 64);
        }
        if (lg == 0 && valid) {
            *(float4*)&el[grow * 4] = make_float4(pl[0], pl[1], pl[2], pl[3]);
            *(float4*)&er[grow * 4] = make_float4(pr[0], pr[1], pr[2], pr[3]);
        }
    }
}

// ---------------- CSR build: partition + LDS counting sort ----------------
// Pass A: per-block x per-range histogram (LDS only). Blocks >= NPB instead
// perform the W transpose+fp16 convert (fused to save a launch).
__global__ __launch_bounds__(512) void partA_k(const int* __restrict__ dst,
                                               int* __restrict__ gcnt,
                                               const float* __restrict__ W1,
                                               const float* __restrict__ W2,
                                               __half* __restrict__ Wt1,
                                               __half* __restrict__ Wt2) {
    if (blockIdx.x >= NPB) {
        int b = blockIdx.x - NPB;  // 0..15
#pragma unroll
        for (int i = 0; i < 4; ++i) {
            int t4 = b * 2048 + i * 512 + threadIdx.x;  // 0..32767
            int layer = t4 >> 14;
            int idx = t4 & 16383;
            int k = idx >> 7, n = idx & 127;
            const float* W = layer ? W2 : W1;
            __half* Wt = layer ? Wt2 : Wt1;
            Wt[n * 128 + k] = __float2half(W[idx]);
        }
        return;
    }
    __shared__ int cnt[NGRP2];
    int b = blockIdx.x, t = threadIdx.x;
    for (int i = t; i < NGRP2; i += 512) cnt[i] = 0;
    __syncthreads();
    int e_beg = b * EPB;
    for (int e = e_beg + t; e < e_beg + EPB; e += 512)
        atomicAdd(&cnt[dst[e] / GR2], 1);
    __syncthreads();
    for (int i = t; i < NGRP2; i += 512) gcnt[i * NPB + b] = cnt[i];
}

// Hierarchical exclusive scan of gcnt (51200 = PSB*1024, g-major).
__global__ __launch_bounds__(1024) void psumA_k(const int* __restrict__ gcnt,
                                                int* __restrict__ psum) {
    __shared__ int sh[1024];
    int b = blockIdx.x, t = threadIdx.x;
    sh[t] = gcnt[b * 1024 + t];
    __syncthreads();
    for (int off = 512; off; off >>= 1) {
        if (t < off) sh[t] += sh[t + off];
        __syncthreads();
    }
    if (t == 0) psum[b] = sh[0];
}

__global__ __launch_bounds__(64) void psumB_k(const int* __restrict__ psum,
                                              int* __restrict__ poffb,
                                              int* __restrict__ rowptr) {
    __shared__ int sh[64];
    int t = threadIdx.x;
    int v = (t < PSB) ? psum[t] : 0;
    sh[t] = v;
    __syncthreads();
    for (int off = 1; off < 64; off <<= 1) {
        int u = (t >= off) ? sh[t - off] : 0;
        __syncthreads();
        sh[t] += u;
        __syncthreads();
    }
    if (t < PSB) poffb[t] = sh[t] - v;
    if (t == 0) rowptr[NN] = EE;
}

__global__ __launch_bounds__(1024) void psumC_k(const int* __restrict__ gcnt,
                                                const int* __restrict__ poffb,
                                                int* __restrict__ poff) {
    __shared__ int sh[1024];
    int b = blockIdx.x, t = threadIdx.x;
    int v = gcnt[b * 1024 + t];
    sh[t] = v;
    __syncthreads();
    for (int off = 1; off < 1024; off <<= 1) {
        int u = (t >= off) ? sh[t - off] : 0;
        __syncthreads();
        sh[t] += u;
        __syncthreads();
    }
    poff[b * 1024 + t] = sh[t] - v + poffb[b];
}

// Pass B: partition edges; PACKED 4B entries: src (17b) | (d%GR2)<<17 (9b).
__global__ __launch_bounds__(512) void partB_k(const int* __restrict__ src,
                                               const int* __restrict__ dst,
                                               const int* __restrict__ poff,
                                               int* __restrict__ ebuf) {
    __shared__ int cur[NGRP2];
    int b = blockIdx.x, t = threadIdx.x;
    for (int i = t; i < NGRP2; i += 512) cur[i] = poff[i * NPB + b];
    __syncthreads();
    int e_beg = b * EPB;
    for (int e = e_beg + t; e < e_beg + EPB; e += 512) {
        int d = dst[e], s = src[e];
        int g = d / GR2;
        int p = atomicAdd(&cur[g], 1);
        ebuf[p] = s | ((d - g * GR2) << 17);
    }
}

// Pass C: per-range LDS counting sort; derives rowptr locally.
__global__ __launch_bounds__(512) void partC_k(const int* __restrict__ ebuf,
                                               const int* __restrict__ poff,
                                               int* __restrict__ rowptr,
                                               int* __restrict__ csr_src) {
    __shared__ int lsrc[CCAP];
    __shared__ int ldeg[512];
    __shared__ int ssc[512];
    __shared__ int lcur[512];
    int g = blockIdx.x, t = threadIdx.x;
    int nbase = g * GR2;
    int beg = poff[g * NPB];
    int end = (g == NGRP2 - 1) ? EE : poff[(g + 1) * NPB];
    ldeg[t] = 0;
    __syncthreads();
    for (int e = beg + t; e < end; e += 512)
        atomicAdd(&ldeg[ebuf[e] >> 17], 1);
    __syncthreads();
    int v = ldeg[t];
    ssc[t] = v;
    __syncthreads();
    for (int off = 1; off < 512; off <<= 1) {
        int u = (t >= off) ? ssc[t - off] : 0;
        __syncthreads();
        ssc[t] += u;
        __syncthreads();
    }
    int ex = ssc[t] - v;
    lcur[t] = ex;
    if (t < GR2) rowptr[nbase + t] = beg + ex;
    __syncthreads();
    for (int e = beg + t; e < end; e += 512) {
        int pk = ebuf[e];
        int p = atomicAdd(&lcur[pk >> 17], 1);
        if (p < CCAP) lsrc[p] = pk & 0x1FFFF;
    }
    __syncthreads();
    int len = end - beg; if (len > CCAP) len = CCAP;
    for (int i = t; i < len; i += 512) csr_src[beg + i] = lsrc[i];
}

// ---------- fused per-node softmax + aggregation ----------
#define BC16(x, I) __uint_as_float(__builtin_amdgcn_ds_swizzle( \
    __float_as_uint(x), ((I) << 5) | 0x10))

#define AGG_STEP(av, hvp, I)                      \
    {                                             \
        float ai = BC16(av, I);                   \
        float2 f = __half22float2((hvp)[I]);      \
        acc0 = fmaf(ai, f.x, acc0);               \
        acc1 = fmaf(ai, f.y, acc1);               \
    }

#define AGG16(av, hvp)                                                       \
    AGG_STEP(av, hvp, 0)  AGG_STEP(av, hvp, 1)  AGG_STEP(av, hvp, 2)         \
    AGG_STEP(av, hvp, 3)  AGG_STEP(av, hvp, 4)  AGG_STEP(av, hvp, 5)         \
    AGG_STEP(av, hvp, 6)  AGG_STEP(av, hvp, 7)  AGG_STEP(av, hvp, 8)         \
    AGG_STEP(av, hvp, 9)  AGG_STEP(av, hvp, 10) AGG_STEP(av, hvp, 11)        \
    AGG_STEP(av, hvp, 12) AGG_STEP(av, hvp, 13) AGG_STEP(av, hvp, 14)        \
    AGG_STEP(av, hvp, 15)

template <int FINAL>
__global__ __launch_bounds__(64) void gat_agg_k(const int* __restrict__ rowptr,
                                                const int* __restrict__ csr_src,
                                                const float* __restrict__ el,
                                                const float* __restrict__ er,
                                                const __half* __restrict__ h,
                                                const float* __restrict__ bias,
                                                void* __restrict__ outv,
                                                const float* __restrict__ Wf,
                                                const float* __restrict__ bf) {
    int wave = blockIdx.x;
    int lane = threadIdx.x;
    int row = rowptr[wave], end = rowptr[wave + 1];
    int hd = lane >> 4, sub = lane & 15;
    float erd = er[wave * 4 + hd];
    const __half2* hbase = (const __half2*)h + lane;  // + si*64 per gather

    float dpart = 0.f, acc0 = 0.f, acc1 = 0.f;
    for (int base = row; base < end; base += 32) {
        int c = end - base;
        int s0 = csr_src[base + (sub < c ? sub : 0)];
        float a0 = 0.f;
        {
            float v = el[s0 * 4 + hd] + erd;
            v = (v >= 0.f) ? v : 0.2f * v;
            if (sub < c) a0 = __expf(v);
        }
        if (c > 16) {
            int i1 = 16 + sub;
            int s1 = csr_src[base + (i1 < c ? i1 : 0)];
            float a1 = 0.f;
            {
                float v = el[s1 * 4 + hd] + erd;
                v = (v >= 0.f) ? v : 0.2f * v;
                if (i1 < c) a1 = __expf(v);
            }
            dpart += a0 + a1;
            __half2 hv[32];
#pragma unroll
            for (int i = 0; i < 16; ++i) {
                int si = __builtin_amdgcn_readlane(s0, i);
                hv[i] = hbase[si * 64];
            }
#pragma unroll
            for (int i = 0; i < 16; ++i) {
                int si = __builtin_amdgcn_readlane(s1, i);
                hv[16 + i] = hbase[si * 64];
            }
            AGG16(a0, hv)
            AGG16(a1, (hv + 16))
        } else {
            dpart += a0;
            __half2 hv[16];
#pragma unroll
            for (int i = 0; i < 16; ++i) {
                int si = __builtin_amdgcn_readlane(s0, i);
                hv[i] = hbase[si * 64];
            }
            AGG16(a0, hv)
        }
    }
    float denom = dpart;
#pragma unroll
    for (int off = 1; off < 16; off <<= 1) denom += __shfl_xor(denom, off, 64);
    float inv = 1.f / fmaxf(denom, 1e-9f);
    float2 bv = *(const float2*)&bias[lane * 2];
    float o0 = acc0 * inv + bv.x;
    float o1 = acc1 * inv + bv.y;

    if (FINAL) {
        float* out = (float*)outv;
        float4 wf = *(const float4*)&Wf[lane * 4];
        float c0 = o0 * wf.x + o1 * wf.z;
        float c1 = o0 * wf.y + o1 * wf.w;
#pragma unroll
        for (int off = 1; off < 64; off <<= 1) {
            c0 += __shfl_xor(c0, off, 64);
            c1 += __shfl_xor(c1, off, 64);
        }
        if (lane == 0) {
            float2 res = make_float2(c0 + bf[0], c1 + bf[1]);
            *(float2*)&out[(size_t)wave * 2] = res;
        }
    } else {
        __half* out = (__half*)outv;
        *(__half2*)&out[(size_t)wave * 128 + lane * 2] = __floats2half2_rn(o0, o1);
    }
}

extern "C" void kernel_launch(void* const* d_in, const int* in_sizes, int n_in,
                              void* d_out, int out_size, void* d_ws, size_t ws_size,
                              hipStream_t stream) {
    const float* x   = (const float*)d_in[0];
    const int*   src = (const int*)d_in[1];
    const int*   dst = (const int*)d_in[2];
    const float* W1  = (const float*)d_in[3];
    const float* al1 = (const float*)d_in[4];
    const float* ar1 = (const float*)d_in[5];
    const float* b1  = (const float*)d_in[6];
    const float* W2  = (const float*)d_in[7];
    const float* al2 = (const float*)d_in[8];
    const float* ar2 = (const float*)d_in[9];
    const float* b2  = (const float*)d_in[10];
    const float* Wf  = (const float*)d_in[11];
    const float* bf  = (const float*)d_in[12];
    float* out = (float*)d_out;

    __half* bufH  = (__half*)d_ws;                       // N*128 fp16 (h)
    __half* bufO  = bufH + (size_t)NN * 128;             // N*128 fp16 (layer1 out)
    float* el     = (float*)(bufO + (size_t)NN * 128);   // N*4
    float* er     = el + NN * 4;                         // N*4
    int* rowptr   = (int*)(er + NN * 4);                 // N+2 (padded even)
    int* csr_src  = rowptr + NN + 2;                     // E
    int* ebuf     = csr_src + EE;                        // E (packed 4B)
    int* gcnt     = ebuf + EE;                           // NGRP2*NPB
    int* poff     = gcnt + NGRP2 * NPB;                  // NGRP2*NPB
    int* psum     = poff + NGRP2 * NPB;                  // PSB
    int* poffb    = psum + PSB;                          // PSB
    __half* Wt1   = (__half*)(poffb + PSB);              // 128*128 fp16
    __half* Wt2   = Wt1 + 128 * 128;                     // 128*128 fp16

    const int T = 256;
    int gGemm = (NN + 127) / 128;    // 128 rows per block

    // CSR build (+fused W transpose in the extra 16 blocks)
    partA_k<<<NPB + 16, 512, 0, stream>>>(dst, gcnt, W1, W2, Wt1, Wt2);
    psumA_k<<<PSB, 1024, 0, stream>>>(gcnt, psum);
    psumB_k<<<1, 64, 0, stream>>>(psum, poffb, rowptr);
    psumC_k<<<PSB, 1024, 0, stream>>>(gcnt, poffb, poff);
    partB_k<<<NPB, 512, 0, stream>>>(src, dst, poff, ebuf);
    partC_k<<<NGRP2, 512, 0, stream>>>(ebuf, poff, rowptr, csr_src);

    // layer 1
    gemm_el_k<0><<<gGemm, T, 0, stream>>>(x, Wt1, al1, ar1, bufH, el, er);
    gat_agg_k<0><<<NN, 64, 0, stream>>>(rowptr, csr_src, el, er, bufH, b1, bufO,
                                        nullptr, nullptr);
    // layer 2 (classifier fused into aggregation epilogue)
    gemm_el_k<1><<<gGemm, T, 0, stream>>>(bufO, Wt2, al2, ar2, bufH, el, er);
    gat_agg_k<1><<<NN, 64, 0, stream>>>(rowptr, csr_src, el, er, bufH, b2, out,
                                        Wf, bf);
}